// Round 1
// baseline (528.878 us; speedup 1.0000x reference)
//
#include <hip/hip_runtime.h>

// Problem dims (fixed by setup_inputs): B=4096, A=2048, F=8
#define AP1   2049            // A+1 rows per sample
#define FEAT  8
#define ROWF  (AP1 * FEAT)    // 16392 floats per sample

// ws layout: ws[0] = sum over b of (pred_count - targ_count)^2
//            ws[1] = sum over valid b of per_sample_mse
//            ws[2] = n_valid

__global__ void init_ws_kernel(float* ws) {
    if (threadIdx.x < 3) ws[threadIdx.x] = 0.0f;
}

__device__ __forceinline__ float block_reduce_sum(float v) {
    // wave-level (64-lane) butterfly
    #pragma unroll
    for (int o = 32; o > 0; o >>= 1) v += __shfl_down(v, o, 64);
    __shared__ float sm[4];
    const int wid  = threadIdx.x >> 6;
    const int lane = threadIdx.x & 63;
    if (lane == 0) sm[wid] = v;
    __syncthreads();
    if (wid == 0) {
        v = (lane < 4) ? sm[lane] : 0.0f;
        v += __shfl_down(v, 2, 64);
        v += __shfl_down(v, 1, 64);
    }
    return v;  // valid in thread 0 only
}

__global__ __launch_bounds__(256) void loss_main_kernel(
        const float* __restrict__ pred,
        const float* __restrict__ targ,
        float* __restrict__ ws) {
    const int b = blockIdx.x;
    const float* pb = pred + (size_t)b * ROWF;
    const float* tb = targ + (size_t)b * ROWF;

    const float tc = tb[0];      // target count (exact small integer in fp32)
    const float pc = pb[0];      // predicted count
    const int count = (int)tc;

    // Actions region: floats [FEAT, FEAT + count*FEAT) of each sample — 16B aligned,
    // count*FEAT divisible by 8 -> count*2 float4 chunks.
    const int nvec = count * 2;
    const float4* p4 = (const float4*)(pb + FEAT);
    const float4* t4 = (const float4*)(tb + FEAT);

    float s = 0.0f;
    for (int i = threadIdx.x; i < nvec; i += blockDim.x) {
        const float4 a = p4[i];
        const float4 c = t4[i];
        const float dx = a.x - c.x;
        const float dy = a.y - c.y;
        const float dz = a.z - c.z;
        const float dw = a.w - c.w;
        s += dx * dx + dy * dy + dz * dz + dw * dw;
    }

    const float total = block_reduce_sum(s);

    if (threadIdx.x == 0) {
        const float d = pc - tc;
        atomicAdd(&ws[0], d * d);
        if (count > 0) {
            atomicAdd(&ws[1], total / (float)(count * FEAT));
            atomicAdd(&ws[2], 1.0f);
        }
    }
}

__global__ void finalize_kernel(const float* __restrict__ ws,
                                float* __restrict__ out, float invB) {
    const float count_loss = ws[0] * invB;
    const float nv = ws[2];
    const float atl = (nv > 0.0f) ? (ws[1] / nv) : 0.0f;
    out[0] = count_loss + 2.0f * atl;   // W_ACTION_COUNT=1, W_ACTION_TENSOR=2
}

extern "C" void kernel_launch(void* const* d_in, const int* in_sizes, int n_in,
                              void* d_out, int out_size, void* d_ws, size_t ws_size,
                              hipStream_t stream) {
    const float* pred = (const float*)d_in[0];
    const float* targ = (const float*)d_in[1];
    float* out = (float*)d_out;
    float* ws  = (float*)d_ws;

    const int B = in_sizes[0] / ROWF;   // 4096

    init_ws_kernel<<<1, 64, 0, stream>>>(ws);
    loss_main_kernel<<<B, 256, 0, stream>>>(pred, targ, ws);
    finalize_kernel<<<1, 1, 0, stream>>>(ws, out, 1.0f / (float)B);
}

// Round 2
// 465.065 us; speedup vs baseline: 1.1372x; 1.1372x over previous
//
#include <hip/hip_runtime.h>

// Problem dims (fixed by setup_inputs): B=4096, A=2048, F=8
#define NB    4096
#define AP1   2049            // A+1 rows per sample
#define FEAT  8
#define ROWF  (AP1 * FEAT)    // 16392 floats per sample

// ws layout (floats):
//   ws[0      .. NB)   per-sample (pred_count - targ_count)^2
//   ws[NB     .. 2NB)  per-sample mse (0 if count==0)
//   ws[2NB    .. 3NB)  per-sample valid flag (0/1)
// Every slot is written unconditionally each launch -> no init needed.

__global__ __launch_bounds__(256) void loss_main_kernel(
        const float* __restrict__ pred,
        const float* __restrict__ targ,
        float* __restrict__ ws) {
    const int b = blockIdx.x;
    const float* pb = pred + (size_t)b * ROWF;
    const float* tb = targ + (size_t)b * ROWF;

    const float tc = tb[0];      // target count (exact small integer in fp32)
    const float pc = pb[0];      // predicted count
    const int count = (int)tc;

    // Actions region: floats [FEAT, FEAT + count*FEAT) — 16B-aligned,
    // count*FEAT divisible by 8 -> count*2 float4 chunks.
    const int nvec = count * 2;
    const float4* p4 = (const float4*)(pb + FEAT);
    const float4* t4 = (const float4*)(tb + FEAT);

    float s = 0.0f;
    int i = (int)threadIdx.x;
    const int stride = 256;

    // 4x unrolled: 8 independent loads in flight per wave before use.
    for (; i + 3 * stride < nvec; i += 4 * stride) {
        const float4 a0 = p4[i];
        const float4 a1 = p4[i + stride];
        const float4 a2 = p4[i + 2 * stride];
        const float4 a3 = p4[i + 3 * stride];
        const float4 c0 = t4[i];
        const float4 c1 = t4[i + stride];
        const float4 c2 = t4[i + 2 * stride];
        const float4 c3 = t4[i + 3 * stride];
        float dx, dy, dz, dw;
        dx = a0.x - c0.x; dy = a0.y - c0.y; dz = a0.z - c0.z; dw = a0.w - c0.w;
        s += dx * dx + dy * dy + dz * dz + dw * dw;
        dx = a1.x - c1.x; dy = a1.y - c1.y; dz = a1.z - c1.z; dw = a1.w - c1.w;
        s += dx * dx + dy * dy + dz * dz + dw * dw;
        dx = a2.x - c2.x; dy = a2.y - c2.y; dz = a2.z - c2.z; dw = a2.w - c2.w;
        s += dx * dx + dy * dy + dz * dz + dw * dw;
        dx = a3.x - c3.x; dy = a3.y - c3.y; dz = a3.z - c3.z; dw = a3.w - c3.w;
        s += dx * dx + dy * dy + dz * dz + dw * dw;
    }
    for (; i < nvec; i += stride) {
        const float4 a = p4[i];
        const float4 c = t4[i];
        const float dx = a.x - c.x;
        const float dy = a.y - c.y;
        const float dz = a.z - c.z;
        const float dw = a.w - c.w;
        s += dx * dx + dy * dy + dz * dz + dw * dw;
    }

    // block reduction
    #pragma unroll
    for (int o = 32; o > 0; o >>= 1) s += __shfl_down(s, o, 64);
    __shared__ float sm[4];
    const int wid  = threadIdx.x >> 6;
    const int lane = threadIdx.x & 63;
    if (lane == 0) sm[wid] = s;
    __syncthreads();

    if (threadIdx.x == 0) {
        const float total = sm[0] + sm[1] + sm[2] + sm[3];
        const float d = pc - tc;
        ws[b] = d * d;
        const bool valid = (count > 0);
        ws[NB + b]     = valid ? (total / (float)(count * FEAT)) : 0.0f;
        ws[2 * NB + b] = valid ? 1.0f : 0.0f;
    }
}

__global__ __launch_bounds__(256) void reduce_kernel(
        const float* __restrict__ ws, float* __restrict__ out) {
    float s0 = 0.0f, s1 = 0.0f, s2 = 0.0f;
    for (int i = threadIdx.x; i < NB; i += 256) {
        s0 += ws[i];
        s1 += ws[NB + i];
        s2 += ws[2 * NB + i];
    }
    #pragma unroll
    for (int o = 32; o > 0; o >>= 1) {
        s0 += __shfl_down(s0, o, 64);
        s1 += __shfl_down(s1, o, 64);
        s2 += __shfl_down(s2, o, 64);
    }
    __shared__ float sm[3][4];
    const int wid  = threadIdx.x >> 6;
    const int lane = threadIdx.x & 63;
    if (lane == 0) { sm[0][wid] = s0; sm[1][wid] = s1; sm[2][wid] = s2; }
    __syncthreads();
    if (threadIdx.x == 0) {
        const float count_sum = sm[0][0] + sm[0][1] + sm[0][2] + sm[0][3];
        const float mse_sum   = sm[1][0] + sm[1][1] + sm[1][2] + sm[1][3];
        const float nv        = sm[2][0] + sm[2][1] + sm[2][2] + sm[2][3];
        const float count_loss = count_sum * (1.0f / (float)NB);
        const float atl = (nv > 0.0f) ? (mse_sum / nv) : 0.0f;
        out[0] = count_loss + 2.0f * atl;   // W_ACTION_COUNT=1, W_ACTION_TENSOR=2
    }
}

extern "C" void kernel_launch(void* const* d_in, const int* in_sizes, int n_in,
                              void* d_out, int out_size, void* d_ws, size_t ws_size,
                              hipStream_t stream) {
    const float* pred = (const float*)d_in[0];
    const float* targ = (const float*)d_in[1];
    float* out = (float*)d_out;
    float* ws  = (float*)d_ws;

    loss_main_kernel<<<NB, 256, 0, stream>>>(pred, targ, ws);
    reduce_kernel<<<1, 256, 0, stream>>>(ws, out);
}